// Round 7
// baseline (232.480 us; speedup 1.0000x reference)
//
#include <hip/hip_runtime.h>
#include <hip/hip_bf16.h>

using short8   = __attribute__((ext_vector_type(8))) short;
using floatx4  = __attribute__((ext_vector_type(4))) float;
using floatx16 = __attribute__((ext_vector_type(16))) float;

#define KDIM 768
#define QSCALE 0.18033688011112042f   // 0.125 * log2(e)
#define N1 (8192 * 768)
#define N2 (2304 * 768)
#define N3 (768 * 768)

__device__ __forceinline__ short f2bf(float f) {
    union { float f; unsigned u; } v; v.f = f;
    unsigned r = v.u + 0x7fffu + ((v.u >> 16) & 1u);
    return (short)(r >> 16);
}

__device__ __forceinline__ unsigned pack2bf(float a, float b) {
    __hip_bfloat162 h = __float22bfloat162_rn(float2{a, b});
    union { __hip_bfloat162 h; unsigned u; } c; c.h = h;
    return c.u;
}

__device__ __forceinline__ float fast_exp2(float x) {
#if __has_builtin(__builtin_amdgcn_exp2f)
    return __builtin_amdgcn_exp2f(x);
#else
    return exp2f(x);
#endif
}

__device__ __forceinline__ void async16(const void* g, void* l) {
    __builtin_amdgcn_global_load_lds((const __attribute__((address_space(1))) void*)g,
                                     (__attribute__((address_space(3))) void*)l, 16, 0, 0);
}

// ---------------- fused fp32 -> bf16 convert for all three inputs ----------------
__global__ void cvt_all(const float* __restrict__ a, const float* __restrict__ b,
                        const float* __restrict__ c, short* __restrict__ oa,
                        short* __restrict__ ob, short* __restrict__ oc) {
    int i = (blockIdx.x * blockDim.x + threadIdx.x) * 4;
    const float* src; short* dst;
    if (i < N1)            { src = a + i;            dst = oa + i; }
    else if (i < N1 + N2)  { src = b + (i - N1);     dst = ob + (i - N1); }
    else if (i < N1+N2+N3) { src = c + (i - N1 - N2); dst = oc + (i - N1 - N2); }
    else return;
    float4 v = *(const float4*)src;
    short4 o;
    o.x = f2bf(v.x); o.y = f2bf(v.y); o.z = f2bf(v.z); o.w = f2bf(v.w);
    *(short4*)dst = o;
}

// ---------------- QKV GEMM + fused scatter/transpose epilogue ----------------
// C[8192,2304] = X @ W^T. Epilogue bounces the 128x128 C-tile through LDS and
// writes Q/K as [bh][s][64] (coalesced 16B) and V directly transposed+sigma-
// permuted as Vt [bh][e][2048] (matching attn's expected key order).
__global__ __launch_bounds__(256) void gemm_qkv(
    const short* __restrict__ X, const short* __restrict__ W,
    const float* __restrict__ bias,
    short* __restrict__ Qb, short* __restrict__ Kb, short* __restrict__ Vt)
{
    __shared__ __attribute__((aligned(16))) short SMEM[128 * 72]; // 18.4 KB; aliases As/Bs/T
    short* As = SMEM;              // 128*32
    short* Bs = SMEM + 128 * 32;   // 128*32
    short* T  = SMEM;              // 128 rows x 72 stride (epilogue bounce)

    int tid = threadIdx.x;
    int w = tid >> 6, l = tid & 63;
    int lane16 = l & 15, quad = l >> 4;
    int wm = w & 1, wn = w >> 1;
    int m0 = blockIdx.y * 128, n0 = blockIdx.x * 128;

    floatx4 acc[4][4] = {};

    int srow = w * 32 + (l >> 2);
    int scol = (l & 3) * 8;
    const short* Xg = X + (size_t)(m0 + srow) * KDIM + scol;
    const short* Wg = W + (size_t)(n0 + srow) * KDIM + scol;
    short* AsW = As + (w * 32) * 32;
    short* BsW = Bs + (w * 32) * 32;

    for (int kb = 0; kb < KDIM; kb += 32) {
        __syncthreads();
        async16(Xg + kb,              AsW);
        async16(Xg + kb + 16 * KDIM,  AsW + 16 * 32);
        async16(Wg + kb,              BsW);
        async16(Wg + kb + 16 * KDIM,  BsW + 16 * 32);
        __syncthreads();
        short8 a[4], b[4];
#pragma unroll
        for (int mt = 0; mt < 4; mt++) a[mt] = *(const short8*)(As + (wm * 64 + mt * 16 + lane16) * 32 + quad * 8);
#pragma unroll
        for (int nt = 0; nt < 4; nt++) b[nt] = *(const short8*)(Bs + (wn * 64 + nt * 16 + lane16) * 32 + quad * 8);
#pragma unroll
        for (int mt = 0; mt < 4; mt++)
#pragma unroll
            for (int nt = 0; nt < 4; nt++)
                acc[mt][nt] = __builtin_amdgcn_mfma_f32_16x16x32_bf16(a[mt], b[nt], acc[mt][nt], 0, 0, 0);
    }

    // ---- fused epilogue: two 64-col groups (each = one head, one qkv type) ----
    int b_  = m0 >> 11;        // batch (block never straddles: 128 | 2048)
    int m0s = m0 & 2047;       // s-offset within batch
#pragma unroll
    for (int g = 0; g < 2; g++) {
        __syncthreads();       // LDS (As/Bs or previous T) safe to overwrite
        if (wn == g) {
#pragma unroll
            for (int mt = 0; mt < 4; mt++)
#pragma unroll
                for (int nt = 0; nt < 4; nt++) {
                    int col = n0 + g * 64 + nt * 16 + lane16;
                    float sc = (col < 768) ? (float)QSCALE : 1.0f;
                    float bv = bias[col];
#pragma unroll
                    for (int r = 0; r < 4; r++) {
                        int row = wm * 64 + mt * 16 + quad * 4 + r;
                        T[row * 72 + nt * 16 + lane16] = f2bf((acc[mt][nt][r] + bv) * sc);
                    }
                }
        }
        __syncthreads();
        int col0 = n0 + g * 64;
        int qkv = (col0 >= 1536) ? 2 : ((col0 >= 768) ? 1 : 0);
        int h = (col0 - qkv * 768) >> 6;
        size_t bh = (size_t)(b_ * 12 + h);
        if (qkv < 2) {
            short* dst = ((qkv == 0) ? Qb : Kb) + bh * 2048 * 64;
#pragma unroll
            for (int u = 0; u < 4; u++) {
                int unit = u * 256 + tid;
                int row = unit >> 3, c = unit & 7;
                short8 v = *(const short8*)(T + row * 72 + c * 8);
                *(short8*)(dst + (size_t)(m0s + row) * 64 + c * 8) = v;
            }
        } else {
            short* dst = Vt + bh * 64 * 2048;
#pragma unroll
            for (int u = 0; u < 4; u++) {
                int unit = u * 256 + tid;
                int e = unit >> 4, sc_ = unit & 15;
                short8 o;
#pragma unroll
                for (int j = 0; j < 8; j++) {
                    int pos = sc_ * 8 + j;
                    int t = pos >> 6, tp = pos & 63;
                    int kp = (tp & 0x33) | ((tp & 4) << 1) | ((tp & 8) >> 1);  // sigma
                    o[j] = T[(t * 64 + kp) * 72 + e];
                }
                *(short8*)(dst + (size_t)e * 2048 + m0s + sc_ * 8) = o;
            }
        }
    }
}

// ---------------- flash attention, 32x32x16 MFMA, transposed QK^T, P in registers ----------------
// (unchanged from round 6 — best known: 74.5 us)
__global__ __launch_bounds__(256, 3) void attn(
    const short* __restrict__ Qb, const short* __restrict__ Kb,
    const short* __restrict__ Vt, short* __restrict__ Ctx)
{
    __shared__ short Ks[512 * 8];
    __shared__ short Vs[512 * 8];
    int tid = threadIdx.x, w = tid >> 6, l = tid & 63;
    int l32 = l & 31, half = l >> 5;
    int qt = blockIdx.x, bh = blockIdx.y;
    const short* Qh  = Qb + (size_t)bh * 2048 * 64;
    const short* Kh  = Kb + (size_t)bh * 2048 * 64;
    const short* Vth = Vt + (size_t)bh * 64 * 2048;
    int qbase = qt * 128 + w * 32;

    const short* kSrc[2];
    const short* vSrc[2];
    short* kDst[2];
    short* vDst[2];
#pragma unroll
    for (int i = 0; i < 2; i++) {
        int slot = i * 256 + tid;
        int row = slot >> 3;
        int g = (slot & 7) ^ (row & 7);
        kSrc[i] = Kh + (size_t)row * 64 + g * 8;
        vSrc[i] = Vth + (size_t)row * 2048 + g * 8;
        kDst[i] = Ks + (size_t)(i * 256 + w * 64) * 8;
        vDst[i] = Vs + (size_t)(i * 256 + w * 64) * 8;
    }

    short8 qf[4];
#pragma unroll
    for (int ks = 0; ks < 4; ks++)
        qf[ks] = *(const short8*)(Qh + (size_t)(qbase + l32) * 64 + ks * 16 + half * 8);

    float lsum = 0.f;
    floatx16 acc[2] = {};
    int sw = l32 & 7;

    for (int kt = 0; kt < 32; kt++) {
        __syncthreads();
#pragma unroll
        for (int i = 0; i < 2; i++) {
            async16(kSrc[i] + (size_t)kt * 64 * 64, kDst[i]);
            async16(vSrc[i] + (size_t)kt * 64,      vDst[i]);
        }
        __syncthreads();

        floatx16 s[2];
#pragma unroll
        for (int nt = 0; nt < 2; nt++) {
            floatx16 c = {};
            int rowb = (nt * 32 + l32) * 8;
#pragma unroll
            for (int ks = 0; ks < 4; ks++) {
                short8 kf = *(const short8*)(Ks + (size_t)(rowb + ((ks * 2 + half) ^ sw)) * 8);
                c = __builtin_amdgcn_mfma_f32_32x32x16_bf16(kf, qf[ks], c, 0, 0, 0);
            }
            s[nt] = c;
        }

        union { short8 s8; unsigned u[4]; } pa[4];
#pragma unroll
        for (int nt = 0; nt < 2; nt++)
#pragma unroll
            for (int r = 0; r < 16; r += 2) {
                float p0 = fast_exp2(s[nt][r]);
                float p1 = fast_exp2(s[nt][r + 1]);
                lsum += p0 + p1;
                pa[2 * nt + (r >> 3)].u[(r & 7) >> 1] = pack2bf(p0, p1);
            }

#pragma unroll
        for (int nt = 0; nt < 2; nt++) {
            int rowb = (nt * 32 + l32) * 8;
#pragma unroll
            for (int ks = 0; ks < 4; ks++) {
                short8 vf = *(const short8*)(Vs + (size_t)(rowb + ((ks * 2 + half) ^ sw)) * 8);
                acc[nt] = __builtin_amdgcn_mfma_f32_32x32x16_bf16(pa[ks].s8, vf, acc[nt], 0, 0, 0);
            }
        }
    }

    float denom = lsum + __shfl_xor(lsum, 32);
    float inv_self = 1.0f / denom;

    int b_ = bh / 12, h = bh % 12;
#pragma unroll
    for (int nt = 0; nt < 2; nt++)
#pragma unroll
        for (int r = 0; r < 16; r++) {
            int qloc = (r & 3) + 8 * (r >> 2) + 4 * half;
            float invq = __shfl(inv_self, qloc);
            int q = qbase + qloc;
            int e = nt * 32 + l32;
            Ctx[((size_t)(b_ * 2048 + q)) * 768 + h * 64 + e] = f2bf(acc[nt][r] * invq);
        }
}

// ---------------- proj GEMM: out[8192,768] = Ctx @ W2^T + b, fp32 out ----------------
// Retiled 64x128 -> grid (6,128) = 768 blocks = even 3 blocks/CU.
__global__ __launch_bounds__(256) void gemm_out(
    const short* __restrict__ Ctx, const short* __restrict__ W,
    const float* __restrict__ bias, float* __restrict__ out)
{
    __shared__ short As[64 * 32];
    __shared__ short Bs[128 * 32];
    int tid = threadIdx.x;
    int w = tid >> 6, l = tid & 63;
    int lane16 = l & 15, quad = l >> 4;
    int m0 = blockIdx.y * 64, n0 = blockIdx.x * 128;

    floatx4 acc[4][2] = {};

    // As: 256 slots (row = tid>>2, chunk = tid&3), linear = tid*16B
    const short* XgA = Ctx + (size_t)(m0 + (tid >> 2)) * KDIM + (tid & 3) * 8;
    short* AsD = As + (size_t)(w * 64) * 8;
    // Bs: 512 slots, 2 per thread
    const short* XgB[2];
    short* BsD[2];
#pragma unroll
    for (int i = 0; i < 2; i++) {
        int unit = i * 256 + tid;
        XgB[i] = W + (size_t)(n0 + (unit >> 2)) * KDIM + (unit & 3) * 8;
        BsD[i] = Bs + (size_t)(i * 256 + w * 64) * 8;
    }

    for (int kb = 0; kb < KDIM; kb += 32) {
        __syncthreads();
        async16(XgA + kb, AsD);
        async16(XgB[0] + kb, BsD[0]);
        async16(XgB[1] + kb, BsD[1]);
        __syncthreads();
        short8 a[4], b[2];
#pragma unroll
        for (int mt = 0; mt < 4; mt++) a[mt] = *(const short8*)(As + (mt * 16 + lane16) * 32 + quad * 8);
#pragma unroll
        for (int nt = 0; nt < 2; nt++) b[nt] = *(const short8*)(Bs + (w * 32 + nt * 16 + lane16) * 32 + quad * 8);
#pragma unroll
        for (int mt = 0; mt < 4; mt++)
#pragma unroll
            for (int nt = 0; nt < 2; nt++)
                acc[mt][nt] = __builtin_amdgcn_mfma_f32_16x16x32_bf16(a[mt], b[nt], acc[mt][nt], 0, 0, 0);
    }

#pragma unroll
    for (int mt = 0; mt < 4; mt++) {
        int row = m0 + mt * 16 + quad * 4;
#pragma unroll
        for (int nt = 0; nt < 2; nt++) {
            int col = n0 + w * 32 + nt * 16 + lane16;
            float bv = bias[col];
#pragma unroll
            for (int r = 0; r < 4; r++)
                out[(size_t)(row + r) * 768 + col] = acc[mt][nt][r] + bv;
        }
    }
}

extern "C" void kernel_launch(void* const* d_in, const int* in_sizes, int n_in,
                              void* d_out, int out_size, void* d_ws, size_t ws_size,
                              hipStream_t stream) {
    const float* hs     = (const float*)d_in[0];
    const float* qkv_w  = (const float*)d_in[1];
    const float* qkv_b  = (const float*)d_in[2];
    const float* proj_w = (const float*)d_in[3];
    const float* proj_b = (const float*)d_in[4];
    float* out = (float*)d_out;

    short* Xb  = (short*)d_ws;                     // 8192*768
    short* W1b = Xb  + (size_t)8192 * 768;         // 2304*768
    short* W2b = W1b + (size_t)2304 * 768;         // 768*768
    short* Qb  = W2b + (size_t)768 * 768;          // 48*2048*64
    short* Kb  = Qb  + (size_t)8192 * 768;
    short* Vt  = Kb  + (size_t)8192 * 768;         // [bh][64][2048] sigma-ordered (written by gemm_qkv)
    short* Ctx = Vt  + (size_t)8192 * 768;         // 8192*768

    int ntot = (N1 + N2 + N3) / 4;
    cvt_all<<<(ntot + 255) / 256, 256, 0, stream>>>(hs, qkv_w, proj_w, Xb, W1b, W2b);

    gemm_qkv<<<dim3(18, 64), 256, 0, stream>>>(Xb, W1b, qkv_b, Qb, Kb, Vt);
    attn<<<dim3(16, 48), 256, 0, stream>>>(Qb, Kb, Vt, Ctx);
    gemm_out<<<dim3(6, 128), 256, 0, stream>>>(Ctx, W2b, proj_b, out);
}